// Round 1
// baseline (837.555 us; speedup 1.0000x reference)
//
#include <hip/hip_runtime.h>

#define BATCH 4
#define CH    192
#define IMG   256
#define PLANE (IMG*IMG)
#define NH    6
#define WSZ   8
#define SHIFT 4

typedef unsigned short u16;
typedef __bf16 bf16x8_t __attribute__((ext_vector_type(8)));
typedef unsigned short u16x8 __attribute__((ext_vector_type(8)));
typedef unsigned short u16x4 __attribute__((ext_vector_type(4)));
typedef float f32x4 __attribute__((ext_vector_type(4)));

__device__ __forceinline__ u16 f2bf(float f) {
  unsigned u = __builtin_bit_cast(unsigned, f);
  return (u16)((u + 0x7FFFu + ((u >> 16) & 1u)) >> 16);
}

__device__ __forceinline__ f32x4 mfma16(u16x8 a, u16x8 b, f32x4 c) {
  return __builtin_amdgcn_mfma_f32_16x16x32_bf16(
      __builtin_bit_cast(bf16x8_t, a), __builtin_bit_cast(bf16x8_t, b), c, 0, 0, 0);
}

// ---- per-(b,c) instance-norm stats: mean + rstd ----
__global__ void stats_kernel(const float* __restrict__ in, float* __restrict__ st) {
  const int plane = blockIdx.x;
  const float4* p = (const float4*)(in + (long)plane * PLANE);
  float s = 0.f, ss = 0.f;
  for (int i = threadIdx.x; i < PLANE/4; i += 256) {
    float4 v = p[i];
    s  += v.x + v.y + v.z + v.w;
    ss += v.x*v.x + v.y*v.y + v.z*v.z + v.w*v.w;
  }
  for (int off = 1; off < 64; off <<= 1) {
    s  += __shfl_xor(s,  off, 64);
    ss += __shfl_xor(ss, off, 64);
  }
  __shared__ float aux[4][2];
  const int w = threadIdx.x >> 6;
  if ((threadIdx.x & 63) == 0) { aux[w][0] = s; aux[w][1] = ss; }
  __syncthreads();
  if (threadIdx.x == 0) {
    float S  = aux[0][0]+aux[1][0]+aux[2][0]+aux[3][0];
    float SS = aux[0][1]+aux[1][1]+aux[2][1]+aux[3][1];
    float mean = S * (1.f/PLANE);
    float var  = SS * (1.f/PLANE) - mean*mean;
    st[plane*2]   = mean;
    st[plane*2+1] = rsqrtf(var + 1e-5f);
  }
}

// ---- fp32 -> bf16 weight conversion ----
__global__ void cvt_kernel(const float* __restrict__ a, const float* __restrict__ b,
                           u16* __restrict__ wa, u16* __restrict__ wb) {
  const int i = blockIdx.x*256 + threadIdx.x;
  if (i < 576*192) wa[i] = f2bf(a[i]);
  if (i < 192*192) wb[i] = f2bf(b[i]);
}

// ---- gamma/beta = cond @ film_w^T + film_b ----
__global__ void film_prep(const float* __restrict__ cond, const float* __restrict__ fw,
                          const float* __restrict__ fb, float* __restrict__ gb) {
  const int i = blockIdx.x*256 + threadIdx.x;
  if (i >= BATCH*384) return;
  const int bb = i / 384, oc = i - bb*384;
  const float* cw = fw + oc*128;
  const float* cv = cond + bb*128;
  float s = fb[oc];
  for (int k = 0; k < 128; ++k) s += cv[k]*cw[k];
  gb[i] = s;
}

// ---- fused shifted-window attention: one block per window ----
// LDS map (bytes):
//  [0,      25600)  Xs   u16[64][200]   normalized X, later O_all
//  [25600,  75776)  QK   u16[64][392]   Q(scaled) cols 0..191, K cols 192..383
//  [75776, 103424)  Vt   u16[192][72]   V transposed [channel][token]
//  [103424,121856)  Ps   u16[8][16][72] per-wave P scratch
//  [25600,  76800)  Pout f32[64][200]   (aliases QK/Vt after attention)
//  [121856,127256)  bias f32[225*6]
//  [127256,128792)  mean/rstd f32[192]*2
__global__ __launch_bounds__(512, 2) void attn_kernel(
    const float* __restrict__ x, const float* __restrict__ st,
    const u16* __restrict__ wq, const u16* __restrict__ wp,
    const float* __restrict__ qkvb, const float* __restrict__ projb,
    const float* __restrict__ relb, float* __restrict__ out)
{
  __shared__ __attribute__((aligned(16))) unsigned char smem[128800];
  u16*   Xs    = (u16*)smem;
  u16*   QK    = (u16*)(smem + 25600);
  u16*   Vt    = (u16*)(smem + 75776);
  u16*   Ps    = (u16*)(smem + 103424);
  float* Pout  = (float*)(smem + 25600);
  float* biasT = (float*)(smem + 121856);
  float* meanS = (float*)(smem + 127256);
  float* rstdS = meanS + 192;

  const int t    = threadIdx.x;
  const int lane = t & 63;
  const int wave = t >> 6;
  const int arow = lane & 15;
  const int kgrp = lane >> 4;

  const int wid = blockIdx.x;
  const int b   = wid >> 10;
  const int wh  = (wid >> 5) & 31;
  const int ww  = wid & 31;

  for (int i = t; i < 1350; i += 512) biasT[i] = relb[i];
  for (int i = t; i < 192; i += 512) {
    meanS[i] = st[(b*192 + i)*2];
    rstdS[i] = st[(b*192 + i)*2 + 1];
  }
  __syncthreads();

  // ---- load + instance-normalize window into LDS (bf16) ----
  const int n  = t & 63;               // token
  const int ay = n >> 3, ax = n & 7;
  const int gy = (wh*8 + ay + SHIFT) & 255;
  const int gx = (ww*8 + ax + SHIFT) & 255;
  const int sp = gy*256 + gx;
  const float* xb = x + (long)b*CH*PLANE;
  for (int it = 0; it < 3; ++it) {
    const int c0 = it*64 + (t >> 6)*8;
    u16x8 pk;
    for (int e = 0; e < 8; ++e) {
      const int c = c0 + e;
      float v = xb[(long)c*PLANE + sp];
      pk[e] = f2bf((v - meanS[c]) * rstdS[c]);
    }
    *(u16x8*)&Xs[n*200 + c0] = pk;
  }
  __syncthreads();

  // ---- QKV GEMM: [64,192] @ [192,576] ----
  u16x8 afr[4][6];
  for (int mt = 0; mt < 4; ++mt)
    for (int ks = 0; ks < 6; ++ks)
      afr[mt][ks] = *(const u16x8*)&Xs[(mt*16 + arow)*200 + ks*32 + kgrp*8];

  for (int nt = wave; nt < 36; nt += 8) {
    f32x4 acc[4] = {{0,0,0,0},{0,0,0,0},{0,0,0,0},{0,0,0,0}};
    const u16* wrow = wq + (nt*16 + arow)*192 + kgrp*8;
    for (int ks = 0; ks < 6; ++ks) {
      u16x8 bfr = *(const u16x8*)(wrow + ks*32);
      for (int mt = 0; mt < 4; ++mt)
        acc[mt] = mfma16(afr[mt][ks], bfr, acc[mt]);
    }
    const int ch = nt*16 + arow;         // global qkv channel (D col = lane&15)
    const float addb = qkvb[ch];
    if (ch < 384) {
      const float mult = (ch < 192) ? 0.17677669529663687f : 1.0f;  // 1/sqrt(32) on Q
      for (int mt = 0; mt < 4; ++mt)
        for (int r = 0; r < 4; ++r)
          QK[(mt*16 + kgrp*4 + r)*392 + ch] = f2bf((acc[mt][r] + addb)*mult);
    } else {
      const int vc = ch - 384;
      for (int mt = 0; mt < 4; ++mt) {
        u16x4 pk;
        for (int r = 0; r < 4; ++r) pk[r] = f2bf(acc[mt][r] + addb);
        *(u16x4*)&Vt[vc*72 + mt*16 + kgrp*4] = pk;  // transposed store
      }
    }
  }
  __syncthreads();

  // ---- attention: 24 (head, mtile) tasks over 8 waves ----
  for (int task = wave; task < 24; task += 8) {
    const int hh = task >> 2, mt = task & 3;
    u16x8 qf = *(const u16x8*)&QK[(mt*16 + arow)*392 + hh*32 + kgrp*8];
    f32x4 sv[4];
    for (int nt = 0; nt < 4; ++nt) {
      u16x8 kf = *(const u16x8*)&QK[(nt*16 + arow)*392 + 192 + hh*32 + kgrp*8];
      f32x4 z = {0,0,0,0};
      sv[nt] = mfma16(qf, kf, z);
    }
    // bias + shifted-window mask, in-register
    float p[4][4];
    for (int r = 0; r < 4; ++r) {
      const int i  = mt*16 + kgrp*4 + r;
      const int iy = i >> 3, ix = i & 7;
      const int ri = ((wh==31) ? (iy<4?1:2) : 0)*3 + ((ww==31) ? (ix<4?1:2) : 0);
      for (int nt = 0; nt < 4; ++nt) {
        const int j  = nt*16 + arow;
        const int jy = j >> 3, jx = j & 7;
        const int rj = ((wh==31) ? (jy<4?1:2) : 0)*3 + ((ww==31) ? (jx<4?1:2) : 0);
        float s = sv[nt][r] + biasT[((iy-jy+7)*15 + (ix-jx+7))*6 + hh];
        if (ri != rj) s -= 100.0f;
        p[nt][r] = s;
      }
    }
    // row softmax: reduce over 4 reg-cols x 16 lanes
    for (int r = 0; r < 4; ++r) {
      float mx = fmaxf(fmaxf(p[0][r], p[1][r]), fmaxf(p[2][r], p[3][r]));
      for (int off = 1; off < 16; off <<= 1) mx = fmaxf(mx, __shfl_xor(mx, off, 64));
      float sum = 0.f;
      for (int nt = 0; nt < 4; ++nt) { p[nt][r] = __expf(p[nt][r] - mx); sum += p[nt][r]; }
      for (int off = 1; off < 16; off <<= 1) sum += __shfl_xor(sum, off, 64);
      const float inv = 1.0f / sum;
      for (int nt = 0; nt < 4; ++nt) p[nt][r] *= inv;
    }
    // P -> LDS (per-wave scratch), reload in A-frag layout
    u16* myP = Ps + wave*16*72;
    for (int r = 0; r < 4; ++r)
      for (int nt = 0; nt < 4; ++nt)
        myP[(kgrp*4 + r)*72 + nt*16 + arow] = f2bf(p[nt][r]);

    f32x4 oacc[2] = {{0,0,0,0},{0,0,0,0}};
    for (int ks = 0; ks < 2; ++ks) {
      u16x8 pf = *(const u16x8*)&myP[arow*72 + ks*32 + kgrp*8];
      for (int nt = 0; nt < 2; ++nt) {
        u16x8 vf = *(const u16x8*)&Vt[(hh*32 + nt*16 + arow)*72 + ks*32 + kgrp*8];
        oacc[nt] = mfma16(pf, vf, oacc[nt]);
      }
    }
    for (int nt = 0; nt < 2; ++nt)
      for (int r = 0; r < 4; ++r)
        Xs[(mt*16 + kgrp*4 + r)*200 + hh*32 + nt*16 + arow] = f2bf(oacc[nt][r]);
  }
  __syncthreads();

  // ---- proj GEMM: [64,192] @ [192,192] ----
  for (int nt = wave; nt < 12; nt += 8) {
    const int ch = nt*16 + arow;
    const float pb = projb[ch];
    f32x4 acc[4];
    for (int mt = 0; mt < 4; ++mt) { f32x4 v = {pb, pb, pb, pb}; acc[mt] = v; }
    const u16* wrow = wp + ch*192 + kgrp*8;
    for (int ks = 0; ks < 6; ++ks) {
      u16x8 bfr = *(const u16x8*)(wrow + ks*32);
      for (int mt = 0; mt < 4; ++mt) {
        u16x8 af = *(const u16x8*)&Xs[(mt*16 + arow)*200 + ks*32 + kgrp*8];
        acc[mt] = mfma16(af, bfr, acc[mt]);
      }
    }
    for (int mt = 0; mt < 4; ++mt)
      for (int r = 0; r < 4; ++r)
        Pout[(mt*16 + kgrp*4 + r)*200 + ch] = acc[mt][r];
  }
  __syncthreads();

  // ---- epilogue: out = x + attn (channel-major coalesced-ish writes) ----
  float* ob = out + (long)b*CH*PLANE;
  for (int it = 0; it < 3; ++it) {
    const int c0 = it*64 + (t >> 6)*8;
    for (int e = 0; e < 8; ++e) {
      const int c = c0 + e;
      ob[(long)c*PLANE + sp] = xb[(long)c*PLANE + sp] + Pout[n*200 + c];
    }
  }
}

// ---- FiLM + residual, in place on d_out ----
__global__ void film_kernel(float* __restrict__ io, const float* __restrict__ st,
                            const float* __restrict__ gb) {
  const long total = (long)BATCH*CH*PLANE/4;
  for (long i = (long)blockIdx.x*blockDim.x + threadIdx.x; i < total;
       i += (long)gridDim.x*blockDim.x) {
    const int plane = (int)(i >> 14);
    const int bb = plane / CH, c = plane - bb*CH;
    const float mean = st[plane*2], rstd = st[plane*2+1];
    const float g  = gb[bb*384 + c];
    const float be = gb[bb*384 + 192 + c];
    float4 v = ((const float4*)io)[i];
    float4 o;
    o.x = v.x + (v.x - mean)*rstd*g + be;
    o.y = v.y + (v.y - mean)*rstd*g + be;
    o.z = v.z + (v.z - mean)*rstd*g + be;
    o.w = v.w + (v.w - mean)*rstd*g + be;
    ((float4*)io)[i] = o;
  }
}

extern "C" void kernel_launch(void* const* d_in, const int* in_sizes, int n_in,
                              void* d_out, int out_size, void* d_ws, size_t ws_size,
                              hipStream_t stream) {
  const float* x      = (const float*)d_in[0];
  const float* cond   = (const float*)d_in[1];
  const float* qkv_w  = (const float*)d_in[2];
  const float* qkv_b  = (const float*)d_in[3];
  const float* proj_w = (const float*)d_in[4];
  const float* proj_b = (const float*)d_in[5];
  const float* relb   = (const float*)d_in[6];
  const float* film_w = (const float*)d_in[7];
  const float* film_b = (const float*)d_in[8];
  float* out = (float*)d_out;

  char* ws = (char*)d_ws;
  float* stats1 = (float*)ws;                    // 768*2 f32
  float* stats2 = (float*)(ws + 6144);           // 768*2 f32
  float* gb     = (float*)(ws + 12288);          // 4*384 f32
  u16*   wq     = (u16*)(ws + 18432);            // 576*192 bf16
  u16*   wp     = (u16*)(ws + 18432 + 221184);   // 192*192 bf16

  stats_kernel<<<768, 256, 0, stream>>>(x, stats1);
  cvt_kernel<<<432, 256, 0, stream>>>(qkv_w, proj_w, wq, wp);
  film_prep<<<6, 256, 0, stream>>>(cond, film_w, film_b, gb);
  attn_kernel<<<4096, 512, 0, stream>>>(x, stats1, wq, wp, qkv_b, proj_b, relb, out);
  stats_kernel<<<768, 256, 0, stream>>>(out, stats2);
  film_kernel<<<2048, 256, 0, stream>>>(out, stats2, gb);
}

// Round 2
// 718.146 us; speedup vs baseline: 1.1663x; 1.1663x over previous
//
#include <hip/hip_runtime.h>

#define BATCH 4
#define CH    192
#define PLANE 65536
#define SHIFT 4

typedef unsigned short u16;
typedef __bf16 bf16x8_t __attribute__((ext_vector_type(8)));
typedef unsigned short u16x8 __attribute__((ext_vector_type(8)));
typedef unsigned short u16x4 __attribute__((ext_vector_type(4)));
typedef float f32x4 __attribute__((ext_vector_type(4)));

__device__ __forceinline__ u16 f2bf(float f) {
  unsigned u = __builtin_bit_cast(unsigned, f);
  return (u16)((u + 0x7FFFu + ((u >> 16) & 1u)) >> 16);
}
__device__ __forceinline__ float bf2f(u16 h) {
  unsigned u = ((unsigned)h) << 16;
  return __builtin_bit_cast(float, u);
}
__device__ __forceinline__ f32x4 mfma16(u16x8 a, u16x8 b, f32x4 c) {
  return __builtin_amdgcn_mfma_f32_16x16x32_bf16(
      __builtin_bit_cast(bf16x8_t, a), __builtin_bit_cast(bf16x8_t, b), c, 0, 0, 0);
}
// granule swizzle: spreads rows differing by 8 (ay) and 1 across banks
__device__ __forceinline__ int swz(int row, int gran) {
  return gran ^ (row & 7) ^ ((row >> 3) & 7);
}

// ---- per-(b,c) instance-norm stats for x: mean + rstd ----
__global__ void stats_kernel(const float* __restrict__ in, float* __restrict__ st) {
  const int plane = blockIdx.x;
  const float4* p = (const float4*)(in + (long)plane * PLANE);
  float s = 0.f, ss = 0.f;
  for (int i = threadIdx.x; i < PLANE/4; i += 256) {
    float4 v = p[i];
    s  += v.x + v.y + v.z + v.w;
    ss += v.x*v.x + v.y*v.y + v.z*v.z + v.w*v.w;
  }
  for (int off = 1; off < 64; off <<= 1) {
    s  += __shfl_xor(s,  off, 64);
    ss += __shfl_xor(ss, off, 64);
  }
  __shared__ float aux[4][2];
  const int w = threadIdx.x >> 6;
  if ((threadIdx.x & 63) == 0) { aux[w][0] = s; aux[w][1] = ss; }
  __syncthreads();
  if (threadIdx.x == 0) {
    float S  = aux[0][0]+aux[1][0]+aux[2][0]+aux[3][0];
    float SS = aux[0][1]+aux[1][1]+aux[2][1]+aux[3][1];
    float mean = S * (1.f/PLANE);
    float var  = SS * (1.f/PLANE) - mean*mean;
    st[plane*2]   = mean;
    st[plane*2+1] = rsqrtf(var + 1e-5f);
  }
}

__global__ void zero_kernel(float* __restrict__ p) {
  p[blockIdx.x*256 + threadIdx.x] = 0.f;
}

__global__ void cvt_kernel(const float* __restrict__ a, const float* __restrict__ b,
                           u16* __restrict__ wa, u16* __restrict__ wb) {
  const int i = blockIdx.x*256 + threadIdx.x;
  if (i < 576*192) wa[i] = f2bf(a[i]);
  if (i < 192*192) wb[i] = f2bf(b[i]);
}

__global__ void film_prep(const float* __restrict__ cond, const float* __restrict__ fw,
                          const float* __restrict__ fb, float* __restrict__ gb) {
  const int i = blockIdx.x*256 + threadIdx.x;
  if (i >= BATCH*384) return;
  const int bb = i / 384, oc = i - bb*384;
  const float* cw = fw + oc*128;
  const float* cv = cond + bb*128;
  float s = fb[oc];
  for (int k = 0; k < 128; ++k) s += cv[k]*cw[k];
  gb[i] = s;
}

// ---- fused shifted-window attention, one block/window, 2 blocks/CU ----
// LDS (bytes): Xs [64][200]u16 @0 (X, later O)   25600
//              G  [64][136]u16 @25600 (Q|K)      17408   } Pout [192][72]u16
//              Vt [64][72] u16 @43008            9216    } aliases @25600
//              Ps [8][16][72]u16 @52224          18432
//              bias f32[1350] @70656             5400
//              mean/rstd f32[192]*2 @76056       1536
__global__ __launch_bounds__(512, 4) void attn_kernel(
    const float* __restrict__ x, const float* __restrict__ st,
    const u16* __restrict__ wq, const u16* __restrict__ wp,
    const float* __restrict__ qkvb, const float* __restrict__ projb,
    const float* __restrict__ relb, float* __restrict__ out,
    float* __restrict__ st2)
{
  __shared__ __attribute__((aligned(16))) unsigned char smem[77592];
  u16*   Xs    = (u16*)smem;
  u16*   G     = (u16*)(smem + 25600);
  u16*   Vt    = (u16*)(smem + 43008);
  u16*   Ps    = (u16*)(smem + 52224);
  u16*   Pout  = (u16*)(smem + 25600);
  float* biasT = (float*)(smem + 70656);
  float* meanS = (float*)(smem + 76056);
  float* rstdS = meanS + 192;

  const int t    = threadIdx.x;
  const int lane = t & 63;
  const int wave = t >> 6;
  const int arow = lane & 15;
  const int kgrp = lane >> 4;

  // XCD-contiguous swizzle: XCD k runs windows [512k, 512k+512)
  const int bid = blockIdx.x;
  const int wid = (bid & 7) * 512 + (bid >> 3);
  const int b   = wid >> 10;
  const int wh  = (wid >> 5) & 31;
  const int ww  = wid & 31;

  for (int i = t; i < 1350; i += 512) biasT[i] = relb[i];
  for (int i = t; i < 192; i += 512) {
    meanS[i] = st[(b*192 + i)*2];
    rstdS[i] = st[(b*192 + i)*2 + 1];
  }
  __syncthreads();

  // ---- stage: float4 loads, normalize, bf16 into Xs; raw x kept in regs ----
  const int cbase = t >> 4;
  const int ay    = (t >> 1) & 7;
  const int half  = t & 1;
  const int gy    = (wh*8 + ay + SHIFT) & 255;
  const int gx0   = (ww*8 + half*4 + SHIFT) & 255;
  const long spo  = (long)gy*256 + gx0;
  const int tok0  = ay*8 + half*4;
  const float* xb = x + (long)b*CH*PLANE;
  float* ob       = out + (long)b*CH*PLANE;

  u16x4 xr[6];
  #pragma unroll
  for (int it = 0; it < 6; ++it) {
    const int c = it*32 + cbase;
    float4 v = *(const float4*)(xb + (long)c*PLANE + spo);
    const float m = meanS[c], r = rstdS[c];
    float va[4] = {v.x, v.y, v.z, v.w};
    #pragma unroll
    for (int j = 0; j < 4; ++j) {
      const int row = tok0 + j;
      Xs[row*200 + (swz(row, c>>3)<<3) + (c&7)] = f2bf((va[j] - m) * r);
      xr[it][j] = f2bf(va[j]);
    }
  }
  __syncthreads();

  // ---- per-2-head-group loop ----
  const int hh = wave >> 2;       // head within group
  const int mt = wave & 3;        // row tile
  u16x4 og[3][2];

  #pragma unroll
  for (int g = 0; g < 3; ++g) {
    // QKV slice GEMM: 12 ntiles of 16 cols over 8 waves
    for (int nt0 = wave; nt0 < 12; nt0 += 8) {
      f32x4 acc[4] = {{0,0,0,0},{0,0,0,0},{0,0,0,0},{0,0,0,0}};
      const int col = nt0*16 + arow;           // 0..191 group-local
      const int mat = col >> 6;                // 0 Q, 1 K, 2 V
      const int ch  = mat*192 + g*64 + (col & 63);
      const u16* wrow = wq + ch*192 + kgrp*8;
      #pragma unroll
      for (int ks = 0; ks < 6; ++ks) {
        u16x8 bfr = *(const u16x8*)(wrow + ks*32);
        #pragma unroll
        for (int m = 0; m < 4; ++m) {
          const int row = m*16 + arow;
          u16x8 af = *(const u16x8*)&Xs[row*200 + (swz(row, ks*4 + kgrp)<<3)];
          acc[m] = mfma16(af, bfr, acc[m]);
        }
      }
      const float addb = qkvb[ch];
      if (mat == 2) {            // V -> transposed [ch][tok]
        const int vc = col & 63;
        #pragma unroll
        for (int m = 0; m < 4; ++m) {
          u16x4 pk;
          #pragma unroll
          for (int r = 0; r < 4; ++r) pk[r] = f2bf(acc[m][r] + addb);
          *(u16x4*)&Vt[vc*72 + m*16 + kgrp*4] = pk;
        }
      } else {                   // Q (scaled) | K -> G
        const float mult = (mat == 0) ? 0.17677669529663687f : 1.0f;
        const int gc = mat*64 + (col & 63);
        #pragma unroll
        for (int m = 0; m < 4; ++m)
          #pragma unroll
          for (int r = 0; r < 4; ++r) {
            const int row = m*16 + kgrp*4 + r;
            G[row*136 + (swz(row, gc>>3)<<3) + (gc&7)] = f2bf((acc[m][r] + addb)*mult);
          }
      }
    }
    __syncthreads();

    // attention: exactly one (hh, mt) task per wave
    const int hd = g*2 + hh;
    u16x8 qf;
    { const int row = mt*16 + arow;
      qf = *(const u16x8*)&G[row*136 + (swz(row, hh*4 + kgrp)<<3)]; }
    f32x4 sv[4];
    #pragma unroll
    for (int nt = 0; nt < 4; ++nt) {
      const int row = nt*16 + arow;
      u16x8 kf = *(const u16x8*)&G[row*136 + (swz(row, 8 + hh*4 + kgrp)<<3)];
      f32x4 z = {0,0,0,0};
      sv[nt] = mfma16(qf, kf, z);
    }
    float p[4][4];
    #pragma unroll
    for (int r = 0; r < 4; ++r) {
      const int i  = mt*16 + kgrp*4 + r;
      const int iy = i >> 3, ix = i & 7;
      const int ri = ((wh==31) ? (iy<4?1:2) : 0)*3 + ((ww==31) ? (ix<4?1:2) : 0);
      #pragma unroll
      for (int nt = 0; nt < 4; ++nt) {
        const int j  = nt*16 + arow;
        const int jy = j >> 3, jx = j & 7;
        const int rj = ((wh==31) ? (jy<4?1:2) : 0)*3 + ((ww==31) ? (jx<4?1:2) : 0);
        float s = sv[nt][r] + biasT[((iy-jy+7)*15 + (ix-jx+7))*6 + hd];
        if (ri != rj) s -= 100.0f;
        p[nt][r] = s;
      }
    }
    #pragma unroll
    for (int r = 0; r < 4; ++r) {
      float mx = fmaxf(fmaxf(p[0][r], p[1][r]), fmaxf(p[2][r], p[3][r]));
      for (int off = 1; off < 16; off <<= 1) mx = fmaxf(mx, __shfl_xor(mx, off, 64));
      float sum = 0.f;
      #pragma unroll
      for (int nt = 0; nt < 4; ++nt) { p[nt][r] = __expf(p[nt][r] - mx); sum += p[nt][r]; }
      for (int off = 1; off < 16; off <<= 1) sum += __shfl_xor(sum, off, 64);
      const float inv = 1.0f / sum;
      #pragma unroll
      for (int nt = 0; nt < 4; ++nt) p[nt][r] *= inv;
    }
    u16* myP = Ps + wave*16*72;
    #pragma unroll
    for (int r = 0; r < 4; ++r)
      #pragma unroll
      for (int nt = 0; nt < 4; ++nt)
        myP[(kgrp*4 + r)*72 + nt*16 + arow] = f2bf(p[nt][r]);

    f32x4 oacc[2] = {{0,0,0,0},{0,0,0,0}};
    #pragma unroll
    for (int ks = 0; ks < 2; ++ks) {
      u16x8 pf = *(const u16x8*)&myP[arow*72 + ks*32 + kgrp*8];
      #pragma unroll
      for (int nt = 0; nt < 2; ++nt) {
        u16x8 vf = *(const u16x8*)&Vt[(hh*32 + nt*16 + arow)*72 + ks*32 + kgrp*8];
        oacc[nt] = mfma16(pf, vf, oacc[nt]);
      }
    }
    #pragma unroll
    for (int nt = 0; nt < 2; ++nt)
      #pragma unroll
      for (int r = 0; r < 4; ++r)
        og[g][nt][r] = f2bf(oacc[nt][r]);
    __syncthreads();
  }

  // ---- O (regs) -> Xs ----
  #pragma unroll
  for (int g = 0; g < 3; ++g)
    #pragma unroll
    for (int nt = 0; nt < 2; ++nt) {
      const int colb = g*64 + hh*32 + nt*16 + arow;
      #pragma unroll
      for (int r = 0; r < 4; ++r) {
        const int row = mt*16 + kgrp*4 + r;
        Xs[row*200 + (swz(row, colb>>3)<<3) + (colb&7)] = og[g][nt][r];
      }
    }
  __syncthreads();

  // ---- proj GEMM: O[64,192] @ Wp^T -> Pout [ch][tok] ----
  for (int nt0 = wave; nt0 < 12; nt0 += 8) {
    const int ch = nt0*16 + arow;
    const float pb = projb[ch];
    f32x4 acc[4];
    #pragma unroll
    for (int m = 0; m < 4; ++m) { f32x4 v = {pb,pb,pb,pb}; acc[m] = v; }
    const u16* wrow = wp + ch*192 + kgrp*8;
    #pragma unroll
    for (int ks = 0; ks < 6; ++ks) {
      u16x8 bfr = *(const u16x8*)(wrow + ks*32);
      #pragma unroll
      for (int m = 0; m < 4; ++m) {
        const int row = m*16 + arow;
        u16x8 af = *(const u16x8*)&Xs[row*200 + (swz(row, ks*4 + kgrp)<<3)];
        acc[m] = mfma16(af, bfr, acc[m]);
      }
    }
    #pragma unroll
    for (int m = 0; m < 4; ++m) {
      u16x4 pk;
      #pragma unroll
      for (int r = 0; r < 4; ++r) pk[r] = f2bf(acc[m][r]);
      *(u16x4*)&Pout[ch*72 + m*16 + kgrp*4] = pk;
    }
  }
  __syncthreads();

  // ---- epilogue: out = x + proj, float4 stores + fused stats2 partial sums ----
  #pragma unroll
  for (int it = 0; it < 6; ++it) {
    const int c = it*32 + cbase;
    u16x4 pv = *(const u16x4*)&Pout[c*72 + tok0];
    float o0 = bf2f(xr[it][0]) + bf2f(pv[0]);
    float o1 = bf2f(xr[it][1]) + bf2f(pv[1]);
    float o2 = bf2f(xr[it][2]) + bf2f(pv[2]);
    float o3 = bf2f(xr[it][3]) + bf2f(pv[3]);
    float4 o = {o0, o1, o2, o3};
    *(float4*)(ob + (long)c*PLANE + spo) = o;
    float s  = o0 + o1 + o2 + o3;
    float ss = o0*o0 + o1*o1 + o2*o2 + o3*o3;
    for (int off = 1; off < 16; off <<= 1) {
      s  += __shfl_xor(s,  off, 64);
      ss += __shfl_xor(ss, off, 64);
    }
    if ((lane & 15) == 0) {
      atomicAdd(&st2[(b*192 + c)*2],     s);
      atomicAdd(&st2[(b*192 + c)*2 + 1], ss);
    }
  }
}

// ---- FiLM + residual, in place on d_out (stats from fused sums) ----
__global__ void film_kernel(float* __restrict__ io, const float* __restrict__ st2,
                            const float* __restrict__ gb) {
  const long total = (long)BATCH*CH*PLANE/4;
  for (long i = (long)blockIdx.x*blockDim.x + threadIdx.x; i < total;
       i += (long)gridDim.x*blockDim.x) {
    const int plane = (int)(i >> 14);
    const int bb = plane / CH, c = plane - bb*CH;
    const float s = st2[plane*2], ssum = st2[plane*2+1];
    const float mean = s * (1.f/PLANE);
    const float var  = ssum * (1.f/PLANE) - mean*mean;
    const float rstd = rsqrtf(var + 1e-5f);
    const float g  = gb[bb*384 + c];
    const float be = gb[bb*384 + 192 + c];
    float4 v = ((const float4*)io)[i];
    float4 o;
    o.x = v.x + (v.x - mean)*rstd*g + be;
    o.y = v.y + (v.y - mean)*rstd*g + be;
    o.z = v.z + (v.z - mean)*rstd*g + be;
    o.w = v.w + (v.w - mean)*rstd*g + be;
    ((float4*)io)[i] = o;
  }
}

extern "C" void kernel_launch(void* const* d_in, const int* in_sizes, int n_in,
                              void* d_out, int out_size, void* d_ws, size_t ws_size,
                              hipStream_t stream) {
  const float* x      = (const float*)d_in[0];
  const float* cond   = (const float*)d_in[1];
  const float* qkv_w  = (const float*)d_in[2];
  const float* qkv_b  = (const float*)d_in[3];
  const float* proj_w = (const float*)d_in[4];
  const float* proj_b = (const float*)d_in[5];
  const float* relb   = (const float*)d_in[6];
  const float* film_w = (const float*)d_in[7];
  const float* film_b = (const float*)d_in[8];
  float* out = (float*)d_out;

  char* ws = (char*)d_ws;
  float* stats1 = (float*)ws;                    // 768*2 f32
  float* st2    = (float*)(ws + 6144);           // 768*2 f32 (sum, sumsq)
  float* gb     = (float*)(ws + 12288);          // 4*384 f32
  u16*   wq     = (u16*)(ws + 18432);            // 576*192 bf16
  u16*   wp     = (u16*)(ws + 18432 + 221184);   // 192*192 bf16

  zero_kernel<<<6, 256, 0, stream>>>(st2);
  stats_kernel<<<768, 256, 0, stream>>>(x, stats1);
  cvt_kernel<<<432, 256, 0, stream>>>(qkv_w, proj_w, wq, wp);
  film_prep<<<6, 256, 0, stream>>>(cond, film_w, film_b, gb);
  attn_kernel<<<4096, 512, 0, stream>>>(x, stats1, wq, wp, qkv_b, proj_b, relb, out, st2);
  film_kernel<<<2048, 256, 0, stream>>>(out, st2, gb);
}